// Round 10
// baseline (448.742 us; speedup 1.0000x reference)
//
#include <hip/hip_runtime.h>
#include <math.h>

#define NB 4
#define NN 50000
#define NC 128
#define NS 64
#define NH 8
#define NE 800000
#define NDH 16
#define RTOT (NB*NN)
#define NCHUNK 192
#define NSB 196           // scan blocks: 196*256 = 50176 >= NN
#define LN_EPS 1e-5f

typedef __bf16 bf16;
typedef bf16 bf16x2 __attribute__((ext_vector_type(2)));
typedef bf16 bf16x4 __attribute__((ext_vector_type(4)));
typedef bf16 bf16x8 __attribute__((ext_vector_type(8)));
typedef float f32x4 __attribute__((ext_vector_type(4)));

__device__ __forceinline__ float wsum64(float v){
  #pragma unroll
  for (int off = 32; off; off >>= 1) v += __shfl_xor(v, off, 64);
  return v;
}
__device__ __forceinline__ float wmax64(float v){
  #pragma unroll
  for (int off = 32; off; off >>= 1) v = fmaxf(v, __shfl_xor(v, off, 64));
  return v;
}

// ---------------- CSR build ----------------
__global__ void k_hist(const int* __restrict__ rows, int* __restrict__ counts){
  int e = blockIdx.x * 256 + threadIdx.x;
  if (e < NE) atomicAdd(&counts[rows[e]], 1);
}

// 3-phase parallel scan (exact, deterministic)
__global__ void k_scan1(const int* __restrict__ counts,
    int* __restrict__ locpre, int* __restrict__ bsum){
  __shared__ int sh[256];
  int t = threadIdx.x;
  int gid = blockIdx.x * 256 + t;
  int v = (gid < NN) ? counts[gid] : 0;
  sh[t] = v;
  __syncthreads();
  #pragma unroll
  for (int off = 1; off < 256; off <<= 1){
    int u = (t >= off) ? sh[t - off] : 0;
    __syncthreads();
    sh[t] += u;
    __syncthreads();
  }
  if (gid < NN) locpre[gid] = sh[t] - v;          // exclusive prefix within block
  if (t == 255) bsum[blockIdx.x] = sh[255];
}

__global__ void k_scan2(const int* __restrict__ bsum,
    int* __restrict__ bpre, int* __restrict__ offsets){
  __shared__ int sh[256];
  int t = threadIdx.x;
  int v = (t < NSB) ? bsum[t] : 0;
  sh[t] = v;
  __syncthreads();
  #pragma unroll
  for (int off = 1; off < 256; off <<= 1){
    int u = (t >= off) ? sh[t - off] : 0;
    __syncthreads();
    sh[t] += u;
    __syncthreads();
  }
  if (t < NSB) bpre[t] = sh[t] - v;
  if (t == 255) offsets[NN] = sh[255];            // == NE
}

__global__ void k_scan3(const int* __restrict__ locpre, const int* __restrict__ bpre,
    int* __restrict__ offsets, int* __restrict__ offcur){
  int gid = blockIdx.x * 256 + threadIdx.x;
  if (gid < NN){
    int o = locpre[gid] + bpre[blockIdx.x];
    offsets[gid] = o;
    offcur[gid]  = o;
  }
}

// edge buffer interleaved: ev[p] = {col, float_bits(val)}
__global__ void k_fill(const int* __restrict__ rows, const int* __restrict__ cols,
    const float* __restrict__ vals, int* __restrict__ offcur,
    int2* __restrict__ ev){
  int e = blockIdx.x * 256 + threadIdx.x;
  if (e < NE){
    int r = rows[e];
    int p = atomicAdd(&offcur[r], 1);
    ev[p] = make_int2(cols[e], __float_as_int(vals[e]));
  }
}

// ------- weight fragment pre-pack: wfrag[(nt*4+ks)*64+lane] = W[nt*16+(lane&15)]
//         [ks*32+(lane>>4)*8 ..+8) as bf16x8 (rows 0..63 front_w, 64..127 slice_w) -------
__global__ void k_wprep(const float* __restrict__ front_w, const float* __restrict__ slice_w,
    bf16* __restrict__ wfrag){
  int t = threadIdx.x;
  for (int f = t; f < 2048; f += 256){
    int nt = f >> 8, ks = (f >> 6) & 3, lane = f & 63;
    int r  = nt * 16 + (lane & 15);
    int k0 = ks * 32 + (lane >> 4) * 8;
    const float* wsrc = (r < NS) ? (front_w + (size_t)r * NC + k0)
                                 : (slice_w + (size_t)(r - NS) * NC + k0);
    bf16x8 o;
    #pragma unroll
    for (int j = 0; j < 8; ++j) o[j] = (bf16)wsrc[j];
    *(bf16x8*)&wfrag[(size_t)f * 8] = o;
  }
}

// ------- fused LN + MFMA logits GEMM — fully wave-independent (no barriers) -------
// BM=64 rows/block. 4 waves; wave w owns rows [w*16,w*16+16) exclusively: LN writes,
// h-writeout, MFMA A-fragment reads, and output stores all touch only the own slice.
// LN: TWO-PASS variance (verified) — do NOT use one-pass E[x^2]-m^2 (round-4 failure).
#define BM 64
#define LDP 136   // bf16 row stride (128 + 8 pad)
__global__ __launch_bounds__(256) void k_logits(const float* __restrict__ x,
    const float* __restrict__ ln_g, const float* __restrict__ ln_be,
    const bf16* __restrict__ wfrag,
    const float* __restrict__ front_b, const float* __restrict__ slice_b,
    bf16* __restrict__ h, bf16* __restrict__ hw, float* __restrict__ base){
  __shared__ bf16 hb[BM][LDP];    // 17.4 KB
  int t = threadIdx.x;
  int lane = t & 63, wv = t >> 6;
  int row0 = blockIdx.x * BM;

  // LayerNorm -> own hb slice (two-pass, 8-row batched; verified op sequence)
  {
    float2 gg = ((const float2*)ln_g)[lane];
    float2 bb = ((const float2*)ln_be)[lane];
    const float2* x2 = (const float2*)x;
    for (int g = 0; g < 16; g += 8){
      int rl = wv * 16 + g;
      float2 v[8];
      #pragma unroll
      for (int i = 0; i < 8; ++i)
        v[i] = x2[(size_t)(row0 + rl + i) * 64 + lane];
      float s[8];
      #pragma unroll
      for (int i = 0; i < 8; ++i) s[i] = v[i].x + v[i].y;
      #pragma unroll
      for (int off = 32; off; off >>= 1)
        #pragma unroll
        for (int i = 0; i < 8; ++i) s[i] += __shfl_xor(s[i], off, 64);
      float dx[8], dy[8], q[8];
      #pragma unroll
      for (int i = 0; i < 8; ++i){
        float m = s[i] * (1.0f / NC);
        dx[i] = v[i].x - m;
        dy[i] = v[i].y - m;
        q[i]  = dx[i]*dx[i] + dy[i]*dy[i];
      }
      #pragma unroll
      for (int off = 32; off; off >>= 1)
        #pragma unroll
        for (int i = 0; i < 8; ++i) q[i] += __shfl_xor(q[i], off, 64);
      #pragma unroll
      for (int i = 0; i < 8; ++i){
        float var = q[i] * (1.0f / NC);
        float rs  = rsqrtf(var + LN_EPS);
        bf16x2 o2 = { (bf16)(dx[i] * rs * gg.x + bb.x),
                      (bf16)(dy[i] * rs * gg.y + bb.y) };
        *(bf16x2*)&hb[rl + i][lane * 2] = o2;
      }
    }
  }
  // wave-local h writeout: lane covers own-slice row (lane>>2), 32 cols
  {
    int r  = wv * 16 + (lane >> 2);
    int c0 = (lane & 3) * 32;
    size_t gr = (size_t)(row0 + r);
    #pragma unroll
    for (int k = 0; k < 4; ++k)
      *(bf16x8*)&h[gr * NC + c0 + k*8] = *(bf16x8*)&hb[r][c0 + k*8];
  }

  int kg = lane >> 4;
  int lr = lane & 15;
  f32x4 acc[8];
  #pragma unroll
  for (int nt = 0; nt < 8; ++nt) acc[nt] = (f32x4){0.f,0.f,0.f,0.f};

  const bf16x8* wf = (const bf16x8*)wfrag;
  #pragma unroll
  for (int ks = 0; ks < 4; ++ks){
    bf16x8 af = *(bf16x8*)&hb[wv*16 + lr][ks*32 + kg*8];
    bf16x8 bw[8];
    #pragma unroll
    for (int nt = 0; nt < 8; ++nt)
      bw[nt] = wf[(nt*4 + ks)*64 + lane];
    #pragma unroll
    for (int nt = 0; nt < 8; ++nt)
      acc[nt] = __builtin_amdgcn_mfma_f32_16x16x32_bf16(af, bw[nt], acc[nt], 0, 0, 0);
  }

  float bias[4];
  #pragma unroll
  for (int nt = 0; nt < 4; ++nt)
    bias[nt] = front_b[nt*16 + lr] + slice_b[nt*16 + lr];

  #pragma unroll
  for (int q = 0; q < 4; ++q){
    int rl = wv*16 + kg*4 + q;
    size_t gr = (size_t)(row0 + rl);
    #pragma unroll
    for (int nt = 0; nt < 4; ++nt){
      float f = acc[nt][q], sl = acc[nt+4][q];
      hw[gr * NS + nt*16 + lr]   = (bf16)f;
      base[gr * NS + nt*16 + lr] = f + sl + bias[nt];
    }
  }
}

// ---------------- gather + fused softmax: one wave per row n, all 4 batches ----------------
// 8-edge unroll: 32 independent gathers in flight per wave. fmaf order on each acc
// chain stays ascending-j (bit-identical to 4-unroll version).
__global__ __launch_bounds__(256) void k_smax(const bf16* __restrict__ hw,
    const int* __restrict__ offsets, const int2* __restrict__ ev,
    float* __restrict__ wbuf){
  int t = threadIdx.x;
  int lane = t & 63, wv = t >> 6;
  int n = blockIdx.x * 4 + wv;          // grid = NN/4 exactly
  int j0 = offsets[n], j1 = offsets[n + 1];

  const bf16* h0 = hw + lane;
  const bf16* h1 = h0 + (size_t)NN * NS;
  const bf16* h2 = h1 + (size_t)NN * NS;
  const bf16* h3 = h2 + (size_t)NN * NS;

  float a0 = wbuf[(size_t)(0*NN + n) * NS + lane];
  float a1 = wbuf[(size_t)(1*NN + n) * NS + lane];
  float a2 = wbuf[(size_t)(2*NN + n) * NS + lane];
  float a3 = wbuf[(size_t)(3*NN + n) * NS + lane];

  for (int jb = j0; jb < j1; jb += 64){
    int cnt = j1 - jb; if (cnt > 64) cnt = 64;
    int jj = jb + lane;
    int2 e = ev[jj < j1 ? jj : j0];
    int u = 0;
    #define EDGE(U) {                                                   \
      int   c  = __builtin_amdgcn_readlane(e.x, (U));                   \
      float vv = __int_as_float(__builtin_amdgcn_readlane(e.y, (U)));   \
      size_t o = (size_t)c << 6;                                        \
      float t0 = (float)h0[o], t1 = (float)h1[o];                       \
      float t2 = (float)h2[o], t3 = (float)h3[o];                       \
      a0 = fmaf(-vv, t0, a0); a1 = fmaf(-vv, t1, a1);                   \
      a2 = fmaf(-vv, t2, a2); a3 = fmaf(-vv, t3, a3); }
    for (; u + 8 <= cnt; u += 8){
      EDGE(u) EDGE(u+1) EDGE(u+2) EDGE(u+3)
      EDGE(u+4) EDGE(u+5) EDGE(u+6) EDGE(u+7)
    }
    for (; u < cnt; ++u){ EDGE(u) }
    #undef EDGE
  }

  float m0=a0, m1=a1, m2=a2, m3=a3;
  #pragma unroll
  for (int off = 32; off; off >>= 1){
    m0 = fmaxf(m0, __shfl_xor(m0, off, 64));
    m1 = fmaxf(m1, __shfl_xor(m1, off, 64));
    m2 = fmaxf(m2, __shfl_xor(m2, off, 64));
    m3 = fmaxf(m3, __shfl_xor(m3, off, 64));
  }
  float e0 = __expf(a0 - m0), e1 = __expf(a1 - m1);
  float e2 = __expf(a2 - m2), e3 = __expf(a3 - m3);
  float s0=e0, s1=e1, s2=e2, s3=e3;
  #pragma unroll
  for (int off = 32; off; off >>= 1){
    s0 += __shfl_xor(s0, off, 64);
    s1 += __shfl_xor(s1, off, 64);
    s2 += __shfl_xor(s2, off, 64);
    s3 += __shfl_xor(s3, off, 64);
  }
  wbuf[(size_t)(0*NN + n) * NS + lane] = e0 / s0;
  wbuf[(size_t)(1*NN + n) * NS + lane] = e1 / s1;
  wbuf[(size_t)(2*NN + n) * NS + lane] = e2 / s2;
  wbuf[(size_t)(3*NN + n) * NS + lane] = e3 / s3;
}

// ------- slices partials: tile[s][c] += w[n][s]*h[n][c]; also wsum partials -------
__global__ __launch_bounds__(256) void k_slices(const float* __restrict__ wbuf,
    const bf16* __restrict__ h, float* __restrict__ partial,
    float* __restrict__ wspart){
  __shared__ float wst[32][NS];   // 8 KB
  int b = blockIdx.y, chunk = blockIdx.x;
  const int per = (NN + NCHUNK - 1) / NCHUNK;   // 261
  int nbeg = chunk * per, nend = min(NN, nbeg + per);
  int t = threadIdx.x;
  int sg = (t >> 4) * 4;
  int cg = (t & 15) * 8;
  float acc[4][8];
  #pragma unroll
  for (int i = 0; i < 4; ++i)
    #pragma unroll
    for (int j = 0; j < 8; ++j) acc[i][j] = 0.f;
  float wsacc = 0.f;
  const float* wb = wbuf + (size_t)b * NN * NS;
  const bf16*  hb = h    + (size_t)b * NN * NC;
  for (int nb = nbeg; nb < nend; nb += 32){
    int cnt = min(32, nend - nb);
    for (int i = t; i < 32 * 32; i += 256){          // float2 staging of w
      int rr = i >> 5, cc = (i & 31) * 2;
      float2 v = (rr < cnt) ? *(const float2*)&wb[(size_t)(nb + rr)*NS + cc]
                            : make_float2(0.f, 0.f);
      *(float2*)&wst[rr][cc] = v;
    }
    __syncthreads();
    #pragma unroll 4
    for (int r = 0; r < cnt; ++r){
      bf16x8 hv8 = *(const bf16x8*)&hb[(size_t)(nb + r)*NC + cg];
      float hv[8];
      #pragma unroll
      for (int j = 0; j < 8; ++j) hv[j] = (float)hv8[j];
      float4 wv = *(const float4*)&wst[r][sg];
      float wv4[4] = { wv.x, wv.y, wv.z, wv.w };
      #pragma unroll
      for (int i = 0; i < 4; ++i)
        #pragma unroll
        for (int j = 0; j < 8; ++j)
          acc[i][j] = fmaf(wv4[i], hv[j], acc[i][j]);
    }
    if (t < NS){
      for (int r = 0; r < cnt; ++r) wsacc += wst[r][t];
    }
    __syncthreads();
  }
  float* dst = partial + (size_t)(b * NCHUNK + chunk) * NS * NC;
  #pragma unroll
  for (int i = 0; i < 4; ++i){
    *(float4*)&dst[(sg + i)*NC + cg]     =
        make_float4(acc[i][0], acc[i][1], acc[i][2], acc[i][3]);
    *(float4*)&dst[(sg + i)*NC + cg + 4] =
        make_float4(acc[i][4], acc[i][5], acc[i][6], acc[i][7]);
  }
  if (t < NS) wspart[(size_t)(b * NCHUNK + chunk) * NS + t] = wsacc;
}

// wsumg[b*64+s] = max(sum_ch wspart, 1e-8)  — one block, deterministic
__global__ void k_wsum(const float* __restrict__ wspart, float* __restrict__ wsumg){
  int t = threadIdx.x;            // 256 = NB*NS
  int b = t >> 6, s = t & 63;
  float a = 0.f;
  for (int ch = 0; ch < NCHUNK; ++ch)
    a += wspart[(size_t)(b * NCHUNK + ch) * NS + s];
  wsumg[t] = fmaxf(a, 1e-8f);
}

__global__ void k_redslices(const float* __restrict__ partial,
    const float* __restrict__ wsumg, float* __restrict__ slices){
  int idx = blockIdx.x * 256 + threadIdx.x;
  if (idx >= NB * NS * NC) return;
  int b  = idx / (NS * NC);
  int sc = idx - b * NS * NC;
  int s  = sc >> 7;
  const float* p = partial + (size_t)b * NCHUNK * NS * NC + sc;
  float acc = 0.f;
  for (int ch = 0; ch < NCHUNK; ++ch) acc += p[(size_t)ch * NS * NC];
  slices[idx] = acc / wsumg[b * NS + s];
}

// ---------------- MHA: one block per (b, head) ----------------
__global__ __launch_bounds__(256) void k_mha(const float* __restrict__ slices,
    const float* __restrict__ in_w, const float* __restrict__ in_b,
    float* __restrict__ obuf){
  __shared__ float sl[NS][NC];
  __shared__ float qs[NS][NDH], ks[NS][NDH], vs[NS][NDH];
  __shared__ float att[NS][NS];
  int b  = blockIdx.x >> 3;
  int hh = blockIdx.x & 7;
  int t  = threadIdx.x;
  const float* slb = slices + (size_t)b * NS * NC;
  for (int i = t; i < NS * NC; i += 256) ((float*)sl)[i] = slb[i];
  __syncthreads();
  for (int p = t; p < NS * NDH; p += 256){
    int s = p >> 4, d = p & 15;
    int rq = hh * NDH + d;
    const float* wq = in_w + (size_t)rq * NC;
    const float* wk = in_w + (size_t)(NC + rq) * NC;
    const float* wv = in_w + (size_t)(2*NC + rq) * NC;
    float aq = 0.f, ak = 0.f, av = 0.f;
    for (int c = 0; c < NC; ++c){
      float hv = sl[s][c];
      aq = fmaf(hv, wq[c], aq); ak = fmaf(hv, wk[c], ak); av = fmaf(hv, wv[c], av);
    }
    qs[s][d] = aq + in_b[rq];
    ks[s][d] = ak + in_b[NC + rq];
    vs[s][d] = av + in_b[2*NC + rq];
  }
  __syncthreads();
  for (int p = t; p < NS * NS; p += 256){
    int si = p >> 6, sj = p & 63;
    float a = 0.f;
    #pragma unroll
    for (int d = 0; d < NDH; ++d) a = fmaf(qs[si][d], ks[sj][d], a);
    att[si][sj] = a * 0.25f;   // 1/sqrt(16)
  }
  __syncthreads();
  int lane = t & 63, wv_ = t >> 6;
  for (int si = wv_; si < NS; si += 4){
    float a  = att[si][lane];
    float m  = wmax64(a);
    float e  = __expf(a - m);
    float sm = wsum64(e);
    att[si][lane] = e / sm;
  }
  __syncthreads();
  for (int p = t; p < NS * NDH; p += 256){
    int s = p >> 4, d = p & 15;
    float a = 0.f;
    #pragma unroll 8
    for (int j = 0; j < NS; ++j) a = fmaf(att[s][j], vs[j][d], a);
    obuf[((size_t)(b*NS + s))*NC + hh*NDH + d] = a;
  }
}

__global__ void k_outproj(const float* __restrict__ obuf,
    const float* __restrict__ out_w, const float* __restrict__ out_b,
    float* __restrict__ so){
  int idx = blockIdx.x * 256 + threadIdx.x;
  if (idx >= NB * NS * NC) return;
  int c  = idx & 127;
  int bs = idx >> 7;
  const float* orow = obuf  + (size_t)bs * NC;
  const float* wrow = out_w + (size_t)c  * NC;
  float a = 0.f;
  #pragma unroll 8
  for (int j = 0; j < NC; ++j) a = fmaf(orow[j], wrow[j], a);
  so[idx] = a + out_b[c];
}

// ---------------- final: out[b,n,:] = weights[b,n,:] @ slices_out[b] ----------------
__global__ __launch_bounds__(256) void k_final(const float* __restrict__ wbuf,
    const float* __restrict__ so, float* __restrict__ out){
  __shared__ float sl[NS][NC];
  __shared__ float wt[4][4][NS];
  int b = blockIdx.y;
  for (int i = threadIdx.x; i < NS * NC; i += 256)
    ((float*)sl)[i] = so[(size_t)b * NS * NC + i];
  __syncthreads();
  int lane = threadIdx.x & 63, wv = threadIdx.x >> 6;
  const float* wb = wbuf + (size_t)b * NN * NS;
  float* ob = out + (size_t)b * NN * NC;
  int step = gridDim.x * 16;
  for (int n0 = (blockIdx.x * 4 + wv) * 4; n0 < NN; n0 += step){
    #pragma unroll
    for (int r = 0; r < 4; ++r)
      wt[wv][r][lane] = wb[(size_t)(n0 + r)*NS + lane];
    float2 a0 = {0,0}, a1 = {0,0}, a2 = {0,0}, a3 = {0,0};
    #pragma unroll 8
    for (int s = 0; s < NS; ++s){
      float2 sv = *(const float2*)&sl[s][lane * 2];
      float w0 = wt[wv][0][s], w1 = wt[wv][1][s], w2 = wt[wv][2][s], w3 = wt[wv][3][s];
      a0.x = fmaf(w0, sv.x, a0.x); a0.y = fmaf(w0, sv.y, a0.y);
      a1.x = fmaf(w1, sv.x, a1.x); a1.y = fmaf(w1, sv.y, a1.y);
      a2.x = fmaf(w2, sv.x, a2.x); a2.y = fmaf(w2, sv.y, a2.y);
      a3.x = fmaf(w3, sv.x, a3.x); a3.y = fmaf(w3, sv.y, a3.y);
    }
    *(float2*)&ob[(size_t)(n0+0)*NC + lane*2] = a0;
    *(float2*)&ob[(size_t)(n0+1)*NC + lane*2] = a1;
    *(float2*)&ob[(size_t)(n0+2)*NC + lane*2] = a2;
    *(float2*)&ob[(size_t)(n0+3)*NC + lane*2] = a3;
  }
}

extern "C" void kernel_launch(void* const* d_in, const int* in_sizes, int n_in,
                              void* d_out, int out_size, void* d_ws, size_t ws_size,
                              hipStream_t stream){
  const float* x          = (const float*)d_in[0];
  const float* adj_values = (const float*)d_in[1];
  const float* ln_g       = (const float*)d_in[2];
  const float* ln_b       = (const float*)d_in[3];
  const float* slice_w    = (const float*)d_in[4];
  const float* slice_b    = (const float*)d_in[5];
  const float* front_w    = (const float*)d_in[6];
  const float* front_b    = (const float*)d_in[7];
  const float* in_w       = (const float*)d_in[8];
  const float* in_b       = (const float*)d_in[9];
  const float* out_w      = (const float*)d_in[10];
  const float* out_b      = (const float*)d_in[11];
  const int*   adj        = (const int*)d_in[12];
  const int*   rows = adj;
  const int*   cols = adj + NE;

  float* outp = (float*)d_out;                       // (B,N,C) out — written only by k_final
  float* wbuf = outp + (size_t)NB * NN * NC;         // (B,N,S) base logits -> weights

  char* wsb = (char*)d_ws;
  size_t off = 0;
  auto alloc = [&](size_t bytes) -> void* {
    void* p = wsb + off;
    off += (bytes + 255) & ~(size_t)255;
    return p;
  };
  bf16*  hw     = (bf16*) alloc((size_t)NB*NN*NS*2);   // 25.6 MB
  bf16*  h16    = (bf16*) alloc((size_t)NB*NN*NC*2);   // 51.2 MB
  int2*  ev     = (int2*) alloc((size_t)NE*8);
  int*   counts = (int*)  alloc((size_t)NN*4);
  int*   offsets= (int*)  alloc((size_t)(NN+1)*4);
  int*   offcur = (int*)  alloc((size_t)NN*4);
  int*   locpre = (int*)  alloc((size_t)NN*4);
  int*   bsum   = (int*)  alloc((size_t)NSB*4);
  int*   bpre   = (int*)  alloc((size_t)NSB*4);
  bf16*  wfrag  = (bf16*) alloc((size_t)128*128*2);    // 32 KB fragment-packed weights
  float* wsumg  = (float*)alloc((size_t)NB*NS*4);
  float* wspart = (float*)alloc((size_t)NB*NCHUNK*NS*4);
  float* obuf   = (float*)alloc((size_t)NB*NS*NC*4);
  float* so     = (float*)alloc((size_t)NB*NS*NC*4);
  float* slices = (float*)alloc((size_t)NB*NS*NC*4);
  float* partial = (float*)hw;   // alias: hw dead after k_smax; partial (25.2 MB) <= hw (25.6 MB)

  hipMemsetAsync(counts, 0, (size_t)NN*4, stream);

  k_hist   <<<(NE+255)/256, 256, 0, stream>>>(rows, counts);
  k_scan1  <<<NSB, 256, 0, stream>>>(counts, locpre, bsum);
  k_scan2  <<<1, 256, 0, stream>>>(bsum, bpre, offsets);
  k_scan3  <<<NSB, 256, 0, stream>>>(locpre, bpre, offsets, offcur);
  k_fill   <<<(NE+255)/256, 256, 0, stream>>>(rows, cols, adj_values, offcur, ev);
  k_wprep  <<<1, 256, 0, stream>>>(front_w, slice_w, wfrag);
  k_logits <<<RTOT/BM, 256, 0, stream>>>(x, ln_g, ln_b, wfrag, front_b, slice_b, h16, hw, wbuf);
  k_smax   <<<NN/4, 256, 0, stream>>>(hw, offsets, ev, wbuf);
  k_slices <<<dim3(NCHUNK, NB), 256, 0, stream>>>(wbuf, h16, partial, wspart);
  k_wsum   <<<1, 256, 0, stream>>>(wspart, wsumg);
  k_redslices<<<(NB*NS*NC+255)/256, 256, 0, stream>>>(partial, wsumg, slices);
  k_mha    <<<NB*NH, 256, 0, stream>>>(slices, in_w, in_b, obuf);
  k_outproj<<<(NB*NS*NC+255)/256, 256, 0, stream>>>(obuf, out_w, out_b, so);
  k_final  <<<dim3(512, NB), 256, 0, stream>>>(wbuf, so, outp);
}

// Round 11
// 435.381 us; speedup vs baseline: 1.0307x; 1.0307x over previous
//
#include <hip/hip_runtime.h>
#include <math.h>

#define NB 4
#define NN 50000
#define NC 128
#define NS 64
#define NH 8
#define NE 800000
#define NDH 16
#define RTOT (NB*NN)
#define NCHUNK 192
#define NSB 196           // scan blocks: 196*256 = 50176 >= NN
#define LN_EPS 1e-5f

typedef __bf16 bf16;
typedef bf16 bf16x2 __attribute__((ext_vector_type(2)));
typedef bf16 bf16x4 __attribute__((ext_vector_type(4)));
typedef bf16 bf16x8 __attribute__((ext_vector_type(8)));
typedef float f32x4 __attribute__((ext_vector_type(4)));

__device__ __forceinline__ float wsum64(float v){
  #pragma unroll
  for (int off = 32; off; off >>= 1) v += __shfl_xor(v, off, 64);
  return v;
}
__device__ __forceinline__ float wmax64(float v){
  #pragma unroll
  for (int off = 32; off; off >>= 1) v = fmaxf(v, __shfl_xor(v, off, 64));
  return v;
}

// ---------------- CSR build ----------------
__global__ void k_hist(const int* __restrict__ rows, int* __restrict__ counts){
  int e = blockIdx.x * 256 + threadIdx.x;
  if (e < NE) atomicAdd(&counts[rows[e]], 1);
}

// 3-phase parallel scan (exact, deterministic)
__global__ void k_scan1(const int* __restrict__ counts,
    int* __restrict__ locpre, int* __restrict__ bsum){
  __shared__ int sh[256];
  int t = threadIdx.x;
  int gid = blockIdx.x * 256 + t;
  int v = (gid < NN) ? counts[gid] : 0;
  sh[t] = v;
  __syncthreads();
  #pragma unroll
  for (int off = 1; off < 256; off <<= 1){
    int u = (t >= off) ? sh[t - off] : 0;
    __syncthreads();
    sh[t] += u;
    __syncthreads();
  }
  if (gid < NN) locpre[gid] = sh[t] - v;          // exclusive prefix within block
  if (t == 255) bsum[blockIdx.x] = sh[255];
}

__global__ void k_scan2(const int* __restrict__ bsum,
    int* __restrict__ bpre, int* __restrict__ offsets){
  __shared__ int sh[256];
  int t = threadIdx.x;
  int v = (t < NSB) ? bsum[t] : 0;
  sh[t] = v;
  __syncthreads();
  #pragma unroll
  for (int off = 1; off < 256; off <<= 1){
    int u = (t >= off) ? sh[t - off] : 0;
    __syncthreads();
    sh[t] += u;
    __syncthreads();
  }
  if (t < NSB) bpre[t] = sh[t] - v;
  if (t == 255) offsets[NN] = sh[255];            // == NE
}

__global__ void k_scan3(const int* __restrict__ locpre, const int* __restrict__ bpre,
    int* __restrict__ offsets, int* __restrict__ offcur){
  int gid = blockIdx.x * 256 + threadIdx.x;
  if (gid < NN){
    int o = locpre[gid] + bpre[blockIdx.x];
    offsets[gid] = o;
    offcur[gid]  = o;
  }
}

// edge buffer interleaved: ev[p] = {col, float_bits(val)}
__global__ void k_fill(const int* __restrict__ rows, const int* __restrict__ cols,
    const float* __restrict__ vals, int* __restrict__ offcur,
    int2* __restrict__ ev){
  int e = blockIdx.x * 256 + threadIdx.x;
  if (e < NE){
    int r = rows[e];
    int p = atomicAdd(&offcur[r], 1);
    ev[p] = make_int2(cols[e], __float_as_int(vals[e]));
  }
}

// ------- weight fragment pre-pack: wfrag[(nt*4+ks)*64+lane] = W[nt*16+(lane&15)]
//         [ks*32+(lane>>4)*8 ..+8) as bf16x8 (rows 0..63 front_w, 64..127 slice_w) -------
__global__ void k_wprep(const float* __restrict__ front_w, const float* __restrict__ slice_w,
    bf16* __restrict__ wfrag){
  int t = threadIdx.x;
  for (int f = t; f < 2048; f += 256){
    int nt = f >> 8, ks = (f >> 6) & 3, lane = f & 63;
    int r  = nt * 16 + (lane & 15);
    int k0 = ks * 32 + (lane >> 4) * 8;
    const float* wsrc = (r < NS) ? (front_w + (size_t)r * NC + k0)
                                 : (slice_w + (size_t)(r - NS) * NC + k0);
    bf16x8 o;
    #pragma unroll
    for (int j = 0; j < 8; ++j) o[j] = (bf16)wsrc[j];
    *(bf16x8*)&wfrag[(size_t)f * 8] = o;
  }
}

// ------- LayerNorm only: pure streaming, no LDS/barriers -------
// One wave per 8 rows (verified TWO-PASS 8-row-batched op sequence — do NOT
// change to one-pass E[x^2]-m^2: round-4 failure 0.0117 -> 0.072).
__global__ __launch_bounds__(256) void k_ln(const float* __restrict__ x,
    const float* __restrict__ ln_g, const float* __restrict__ ln_be,
    bf16* __restrict__ h){
  int t = threadIdx.x;
  int lane = t & 63, wv = t >> 6;
  int r0 = blockIdx.x * 32 + wv * 8;       // grid = RTOT/32
  float2 gg = ((const float2*)ln_g)[lane];
  float2 bb = ((const float2*)ln_be)[lane];
  const float2* x2 = (const float2*)x;
  float2 v[8];
  #pragma unroll
  for (int i = 0; i < 8; ++i)
    v[i] = x2[(size_t)(r0 + i) * 64 + lane];
  float s[8];
  #pragma unroll
  for (int i = 0; i < 8; ++i) s[i] = v[i].x + v[i].y;
  #pragma unroll
  for (int off = 32; off; off >>= 1)
    #pragma unroll
    for (int i = 0; i < 8; ++i) s[i] += __shfl_xor(s[i], off, 64);
  float dx[8], dy[8], q[8];
  #pragma unroll
  for (int i = 0; i < 8; ++i){
    float m = s[i] * (1.0f / NC);
    dx[i] = v[i].x - m;
    dy[i] = v[i].y - m;
    q[i]  = dx[i]*dx[i] + dy[i]*dy[i];
  }
  #pragma unroll
  for (int off = 32; off; off >>= 1)
    #pragma unroll
    for (int i = 0; i < 8; ++i) q[i] += __shfl_xor(q[i], off, 64);
  #pragma unroll
  for (int i = 0; i < 8; ++i){
    float var = q[i] * (1.0f / NC);
    float rs  = rsqrtf(var + LN_EPS);
    bf16x2 o2 = { (bf16)(dx[i] * rs * gg.x + bb.x),
                  (bf16)(dy[i] * rs * gg.y + bb.y) };
    *(bf16x2*)&h[(size_t)(r0 + i) * NC + lane * 2] = o2;
  }
}

// ------- MFMA logits GEMM: A-fragments direct from global h16, no LDS -------
// BM=64 rows/block, 4 waves, wave w owns rows [w*16,w*16+16).
// Same bf16 inputs/fragment layout as verified fused version -> bit-identical.
#define BM 64
__global__ __launch_bounds__(256) void k_gemm(const bf16* __restrict__ h,
    const bf16* __restrict__ wfrag,
    const float* __restrict__ front_b, const float* __restrict__ slice_b,
    bf16* __restrict__ hw, float* __restrict__ base){
  int t = threadIdx.x;
  int lane = t & 63, wv = t >> 6;
  int row0 = blockIdx.x * BM;
  int kg = lane >> 4;
  int lr = lane & 15;

  f32x4 acc[8];
  #pragma unroll
  for (int nt = 0; nt < 8; ++nt) acc[nt] = (f32x4){0.f,0.f,0.f,0.f};

  const bf16* arow = h + (size_t)(row0 + wv*16 + lr) * NC;
  const bf16x8* wf = (const bf16x8*)wfrag;
  #pragma unroll
  for (int ks = 0; ks < 4; ++ks){
    bf16x8 af = *(const bf16x8*)&arow[ks*32 + kg*8];
    bf16x8 bw[8];
    #pragma unroll
    for (int nt = 0; nt < 8; ++nt)
      bw[nt] = wf[(nt*4 + ks)*64 + lane];
    #pragma unroll
    for (int nt = 0; nt < 8; ++nt)
      acc[nt] = __builtin_amdgcn_mfma_f32_16x16x32_bf16(af, bw[nt], acc[nt], 0, 0, 0);
  }

  float bias[4];
  #pragma unroll
  for (int nt = 0; nt < 4; ++nt)
    bias[nt] = front_b[nt*16 + lr] + slice_b[nt*16 + lr];

  #pragma unroll
  for (int q = 0; q < 4; ++q){
    int rl = wv*16 + kg*4 + q;
    size_t gr = (size_t)(row0 + rl);
    #pragma unroll
    for (int nt = 0; nt < 4; ++nt){
      float f = acc[nt][q], sl = acc[nt+4][q];
      hw[gr * NS + nt*16 + lr]   = (bf16)f;
      base[gr * NS + nt*16 + lr] = f + sl + bias[nt];
    }
  }
}

// ---------------- gather + fused softmax: one wave per row n, all 4 batches ----------------
__global__ __launch_bounds__(256) void k_smax(const bf16* __restrict__ hw,
    const int* __restrict__ offsets, const int2* __restrict__ ev,
    float* __restrict__ wbuf){
  int t = threadIdx.x;
  int lane = t & 63, wv = t >> 6;
  int n = blockIdx.x * 4 + wv;          // grid = NN/4 exactly
  int j0 = offsets[n], j1 = offsets[n + 1];

  const bf16* h0 = hw + lane;
  const bf16* h1 = h0 + (size_t)NN * NS;
  const bf16* h2 = h1 + (size_t)NN * NS;
  const bf16* h3 = h2 + (size_t)NN * NS;

  float a0 = wbuf[(size_t)(0*NN + n) * NS + lane];
  float a1 = wbuf[(size_t)(1*NN + n) * NS + lane];
  float a2 = wbuf[(size_t)(2*NN + n) * NS + lane];
  float a3 = wbuf[(size_t)(3*NN + n) * NS + lane];

  for (int jb = j0; jb < j1; jb += 64){
    int cnt = j1 - jb; if (cnt > 64) cnt = 64;
    int jj = jb + lane;
    int2 e = ev[jj < j1 ? jj : j0];
    int u = 0;
    #define EDGE(U) {                                                   \
      int   c  = __builtin_amdgcn_readlane(e.x, (U));                   \
      float vv = __int_as_float(__builtin_amdgcn_readlane(e.y, (U)));   \
      size_t o = (size_t)c << 6;                                        \
      float t0 = (float)h0[o], t1 = (float)h1[o];                       \
      float t2 = (float)h2[o], t3 = (float)h3[o];                       \
      a0 = fmaf(-vv, t0, a0); a1 = fmaf(-vv, t1, a1);                   \
      a2 = fmaf(-vv, t2, a2); a3 = fmaf(-vv, t3, a3); }
    for (; u + 8 <= cnt; u += 8){
      EDGE(u) EDGE(u+1) EDGE(u+2) EDGE(u+3)
      EDGE(u+4) EDGE(u+5) EDGE(u+6) EDGE(u+7)
    }
    for (; u < cnt; ++u){ EDGE(u) }
    #undef EDGE
  }

  float m0=a0, m1=a1, m2=a2, m3=a3;
  #pragma unroll
  for (int off = 32; off; off >>= 1){
    m0 = fmaxf(m0, __shfl_xor(m0, off, 64));
    m1 = fmaxf(m1, __shfl_xor(m1, off, 64));
    m2 = fmaxf(m2, __shfl_xor(m2, off, 64));
    m3 = fmaxf(m3, __shfl_xor(m3, off, 64));
  }
  float e0 = __expf(a0 - m0), e1 = __expf(a1 - m1);
  float e2 = __expf(a2 - m2), e3 = __expf(a3 - m3);
  float s0=e0, s1=e1, s2=e2, s3=e3;
  #pragma unroll
  for (int off = 32; off; off >>= 1){
    s0 += __shfl_xor(s0, off, 64);
    s1 += __shfl_xor(s1, off, 64);
    s2 += __shfl_xor(s2, off, 64);
    s3 += __shfl_xor(s3, off, 64);
  }
  wbuf[(size_t)(0*NN + n) * NS + lane] = e0 / s0;
  wbuf[(size_t)(1*NN + n) * NS + lane] = e1 / s1;
  wbuf[(size_t)(2*NN + n) * NS + lane] = e2 / s2;
  wbuf[(size_t)(3*NN + n) * NS + lane] = e3 / s3;
}

// ------- slices partials: tile[s][c] += w[n][s]*h[n][c]; also wsum partials -------
__global__ __launch_bounds__(256) void k_slices(const float* __restrict__ wbuf,
    const bf16* __restrict__ h, float* __restrict__ partial,
    float* __restrict__ wspart){
  __shared__ float wst[32][NS];   // 8 KB
  int b = blockIdx.y, chunk = blockIdx.x;
  const int per = (NN + NCHUNK - 1) / NCHUNK;   // 261
  int nbeg = chunk * per, nend = min(NN, nbeg + per);
  int t = threadIdx.x;
  int sg = (t >> 4) * 4;
  int cg = (t & 15) * 8;
  float acc[4][8];
  #pragma unroll
  for (int i = 0; i < 4; ++i)
    #pragma unroll
    for (int j = 0; j < 8; ++j) acc[i][j] = 0.f;
  float wsacc = 0.f;
  const float* wb = wbuf + (size_t)b * NN * NS;
  const bf16*  hb = h    + (size_t)b * NN * NC;
  for (int nb = nbeg; nb < nend; nb += 32){
    int cnt = min(32, nend - nb);
    for (int i = t; i < 32 * 32; i += 256){          // float2 staging of w
      int rr = i >> 5, cc = (i & 31) * 2;
      float2 v = (rr < cnt) ? *(const float2*)&wb[(size_t)(nb + rr)*NS + cc]
                            : make_float2(0.f, 0.f);
      *(float2*)&wst[rr][cc] = v;
    }
    __syncthreads();
    #pragma unroll 4
    for (int r = 0; r < cnt; ++r){
      bf16x8 hv8 = *(const bf16x8*)&hb[(size_t)(nb + r)*NC + cg];
      float hv[8];
      #pragma unroll
      for (int j = 0; j < 8; ++j) hv[j] = (float)hv8[j];
      float4 wv = *(const float4*)&wst[r][sg];
      float wv4[4] = { wv.x, wv.y, wv.z, wv.w };
      #pragma unroll
      for (int i = 0; i < 4; ++i)
        #pragma unroll
        for (int j = 0; j < 8; ++j)
          acc[i][j] = fmaf(wv4[i], hv[j], acc[i][j]);
    }
    if (t < NS){
      for (int r = 0; r < cnt; ++r) wsacc += wst[r][t];
    }
    __syncthreads();
  }
  float* dst = partial + (size_t)(b * NCHUNK + chunk) * NS * NC;
  #pragma unroll
  for (int i = 0; i < 4; ++i){
    *(float4*)&dst[(sg + i)*NC + cg]     =
        make_float4(acc[i][0], acc[i][1], acc[i][2], acc[i][3]);
    *(float4*)&dst[(sg + i)*NC + cg + 4] =
        make_float4(acc[i][4], acc[i][5], acc[i][6], acc[i][7]);
  }
  if (t < NS) wspart[(size_t)(b * NCHUNK + chunk) * NS + t] = wsacc;
}

// wsumg[b*64+s] = max(sum_ch wspart, 1e-8)  — one block, deterministic
__global__ void k_wsum(const float* __restrict__ wspart, float* __restrict__ wsumg){
  int t = threadIdx.x;            // 256 = NB*NS
  int b = t >> 6, s = t & 63;
  float a = 0.f;
  for (int ch = 0; ch < NCHUNK; ++ch)
    a += wspart[(size_t)(b * NCHUNK + ch) * NS + s];
  wsumg[t] = fmaxf(a, 1e-8f);
}

__global__ void k_redslices(const float* __restrict__ partial,
    const float* __restrict__ wsumg, float* __restrict__ slices){
  int idx = blockIdx.x * 256 + threadIdx.x;
  if (idx >= NB * NS * NC) return;
  int b  = idx / (NS * NC);
  int sc = idx - b * NS * NC;
  int s  = sc >> 7;
  const float* p = partial + (size_t)b * NCHUNK * NS * NC + sc;
  float acc = 0.f;
  for (int ch = 0; ch < NCHUNK; ++ch) acc += p[(size_t)ch * NS * NC];
  slices[idx] = acc / wsumg[b * NS + s];
}

// ---------------- MHA: one block per (b, head) ----------------
__global__ __launch_bounds__(256) void k_mha(const float* __restrict__ slices,
    const float* __restrict__ in_w, const float* __restrict__ in_b,
    float* __restrict__ obuf){
  __shared__ float sl[NS][NC];
  __shared__ float qs[NS][NDH], ks[NS][NDH], vs[NS][NDH];
  __shared__ float att[NS][NS];
  int b  = blockIdx.x >> 3;
  int hh = blockIdx.x & 7;
  int t  = threadIdx.x;
  const float* slb = slices + (size_t)b * NS * NC;
  for (int i = t; i < NS * NC; i += 256) ((float*)sl)[i] = slb[i];
  __syncthreads();
  for (int p = t; p < NS * NDH; p += 256){
    int s = p >> 4, d = p & 15;
    int rq = hh * NDH + d;
    const float* wq = in_w + (size_t)rq * NC;
    const float* wk = in_w + (size_t)(NC + rq) * NC;
    const float* wv = in_w + (size_t)(2*NC + rq) * NC;
    float aq = 0.f, ak = 0.f, av = 0.f;
    for (int c = 0; c < NC; ++c){
      float hv = sl[s][c];
      aq = fmaf(hv, wq[c], aq); ak = fmaf(hv, wk[c], ak); av = fmaf(hv, wv[c], av);
    }
    qs[s][d] = aq + in_b[rq];
    ks[s][d] = ak + in_b[NC + rq];
    vs[s][d] = av + in_b[2*NC + rq];
  }
  __syncthreads();
  for (int p = t; p < NS * NS; p += 256){
    int si = p >> 6, sj = p & 63;
    float a = 0.f;
    #pragma unroll
    for (int d = 0; d < NDH; ++d) a = fmaf(qs[si][d], ks[sj][d], a);
    att[si][sj] = a * 0.25f;   // 1/sqrt(16)
  }
  __syncthreads();
  int lane = t & 63, wv_ = t >> 6;
  for (int si = wv_; si < NS; si += 4){
    float a  = att[si][lane];
    float m  = wmax64(a);
    float e  = __expf(a - m);
    float sm = wsum64(e);
    att[si][lane] = e / sm;
  }
  __syncthreads();
  for (int p = t; p < NS * NDH; p += 256){
    int s = p >> 4, d = p & 15;
    float a = 0.f;
    #pragma unroll 8
    for (int j = 0; j < NS; ++j) a = fmaf(att[s][j], vs[j][d], a);
    obuf[((size_t)(b*NS + s))*NC + hh*NDH + d] = a;
  }
}

__global__ void k_outproj(const float* __restrict__ obuf,
    const float* __restrict__ out_w, const float* __restrict__ out_b,
    float* __restrict__ so){
  int idx = blockIdx.x * 256 + threadIdx.x;
  if (idx >= NB * NS * NC) return;
  int c  = idx & 127;
  int bs = idx >> 7;
  const float* orow = obuf  + (size_t)bs * NC;
  const float* wrow = out_w + (size_t)c  * NC;
  float a = 0.f;
  #pragma unroll 8
  for (int j = 0; j < NC; ++j) a = fmaf(orow[j], wrow[j], a);
  so[idx] = a + out_b[c];
}

// ---------------- final: out[b,n,:] = weights[b,n,:] @ slices_out[b] ----------------
__global__ __launch_bounds__(256) void k_final(const float* __restrict__ wbuf,
    const float* __restrict__ so, float* __restrict__ out){
  __shared__ float sl[NS][NC];
  __shared__ float wt[4][4][NS];
  int b = blockIdx.y;
  for (int i = threadIdx.x; i < NS * NC; i += 256)
    ((float*)sl)[i] = so[(size_t)b * NS * NC + i];
  __syncthreads();
  int lane = threadIdx.x & 63, wv = threadIdx.x >> 6;
  const float* wb = wbuf + (size_t)b * NN * NS;
  float* ob = out + (size_t)b * NN * NC;
  int step = gridDim.x * 16;
  for (int n0 = (blockIdx.x * 4 + wv) * 4; n0 < NN; n0 += step){
    #pragma unroll
    for (int r = 0; r < 4; ++r)
      wt[wv][r][lane] = wb[(size_t)(n0 + r)*NS + lane];
    float2 a0 = {0,0}, a1 = {0,0}, a2 = {0,0}, a3 = {0,0};
    #pragma unroll 8
    for (int s = 0; s < NS; ++s){
      float2 sv = *(const float2*)&sl[s][lane * 2];
      float w0 = wt[wv][0][s], w1 = wt[wv][1][s], w2 = wt[wv][2][s], w3 = wt[wv][3][s];
      a0.x = fmaf(w0, sv.x, a0.x); a0.y = fmaf(w0, sv.y, a0.y);
      a1.x = fmaf(w1, sv.x, a1.x); a1.y = fmaf(w1, sv.y, a1.y);
      a2.x = fmaf(w2, sv.x, a2.x); a2.y = fmaf(w2, sv.y, a2.y);
      a3.x = fmaf(w3, sv.x, a3.x); a3.y = fmaf(w3, sv.y, a3.y);
    }
    *(float2*)&ob[(size_t)(n0+0)*NC + lane*2] = a0;
    *(float2*)&ob[(size_t)(n0+1)*NC + lane*2] = a1;
    *(float2*)&ob[(size_t)(n0+2)*NC + lane*2] = a2;
    *(float2*)&ob[(size_t)(n0+3)*NC + lane*2] = a3;
  }
}

extern "C" void kernel_launch(void* const* d_in, const int* in_sizes, int n_in,
                              void* d_out, int out_size, void* d_ws, size_t ws_size,
                              hipStream_t stream){
  const float* x          = (const float*)d_in[0];
  const float* adj_values = (const float*)d_in[1];
  const float* ln_g       = (const float*)d_in[2];
  const float* ln_b       = (const float*)d_in[3];
  const float* slice_w    = (const float*)d_in[4];
  const float* slice_b    = (const float*)d_in[5];
  const float* front_w    = (const float*)d_in[6];
  const float* front_b    = (const float*)d_in[7];
  const float* in_w       = (const float*)d_in[8];
  const float* in_b       = (const float*)d_in[9];
  const float* out_w      = (const float*)d_in[10];
  const float* out_b      = (const float*)d_in[11];
  const int*   adj        = (const int*)d_in[12];
  const int*   rows = adj;
  const int*   cols = adj + NE;

  float* outp = (float*)d_out;                       // (B,N,C) out — written only by k_final
  float* wbuf = outp + (size_t)NB * NN * NC;         // (B,N,S) base logits -> weights

  char* wsb = (char*)d_ws;
  size_t off = 0;
  auto alloc = [&](size_t bytes) -> void* {
    void* p = wsb + off;
    off += (bytes + 255) & ~(size_t)255;
    return p;
  };
  bf16*  hw     = (bf16*) alloc((size_t)NB*NN*NS*2);   // 25.6 MB
  bf16*  h16    = (bf16*) alloc((size_t)NB*NN*NC*2);   // 51.2 MB
  int2*  ev     = (int2*) alloc((size_t)NE*8);
  int*   counts = (int*)  alloc((size_t)NN*4);
  int*   offsets= (int*)  alloc((size_t)(NN+1)*4);
  int*   offcur = (int*)  alloc((size_t)NN*4);
  int*   locpre = (int*)  alloc((size_t)NN*4);
  int*   bsum   = (int*)  alloc((size_t)NSB*4);
  int*   bpre   = (int*)  alloc((size_t)NSB*4);
  bf16*  wfrag  = (bf16*) alloc((size_t)128*128*2);    // 32 KB fragment-packed weights
  float* wsumg  = (float*)alloc((size_t)NB*NS*4);
  float* wspart = (float*)alloc((size_t)NB*NCHUNK*NS*4);
  float* obuf   = (float*)alloc((size_t)NB*NS*NC*4);
  float* so     = (float*)alloc((size_t)NB*NS*NC*4);
  float* slices = (float*)alloc((size_t)NB*NS*NC*4);
  float* partial = (float*)hw;   // alias: hw dead after k_smax; partial (25.2 MB) <= hw (25.6 MB)

  hipMemsetAsync(counts, 0, (size_t)NN*4, stream);

  k_hist   <<<(NE+255)/256, 256, 0, stream>>>(rows, counts);
  k_scan1  <<<NSB, 256, 0, stream>>>(counts, locpre, bsum);
  k_scan2  <<<1, 256, 0, stream>>>(bsum, bpre, offsets);
  k_scan3  <<<NSB, 256, 0, stream>>>(locpre, bpre, offsets, offcur);
  k_fill   <<<(NE+255)/256, 256, 0, stream>>>(rows, cols, adj_values, offcur, ev);
  k_wprep  <<<1, 256, 0, stream>>>(front_w, slice_w, wfrag);
  k_ln     <<<RTOT/32, 256, 0, stream>>>(x, ln_g, ln_b, h16);
  k_gemm   <<<RTOT/BM, 256, 0, stream>>>(h16, wfrag, front_b, slice_b, hw, wbuf);
  k_smax   <<<NN/4, 256, 0, stream>>>(hw, offsets, ev, wbuf);
  k_slices <<<dim3(NCHUNK, NB), 256, 0, stream>>>(wbuf, h16, partial, wspart);
  k_wsum   <<<1, 256, 0, stream>>>(wspart, wsumg);
  k_redslices<<<(NB*NS*NC+255)/256, 256, 0, stream>>>(partial, wsumg, slices);
  k_mha    <<<NB*NH, 256, 0, stream>>>(slices, in_w, in_b, obuf);
  k_outproj<<<(NB*NS*NC+255)/256, 256, 0, stream>>>(obuf, out_w, out_b, so);
  k_final  <<<dim3(512, NB), 256, 0, stream>>>(wbuf, so, outp);
}